// Round 13
// baseline (42.674 us; speedup 1.0000x reference)
//
#include <hip/hip_runtime.h>
#include <hip/hip_bf16.h>

#define UNITS 64
#define IFEAT 256
#define OFEAT 256

typedef __attribute__((ext_vector_type(8))) short v8s;   // 8 bf16 (4 VGPRs)
typedef __attribute__((ext_vector_type(4))) float v4f;   // MFMA acc / global f32x4

// pack 2 floats -> u32 of 2 bf16 (RNE) — compiler emits v_cvt_pk_bf16_f32
static __device__ __forceinline__ unsigned int pk2(float a, float b) {
    union { __hip_bfloat162 h; unsigned int u; } c;
    c.h = __float22bfloat162_rn(float2{a, b});
    return c.u;
}
static __device__ __forceinline__ v8s pk8(const float* r) {
    union { uint4 u4; v8s s8; } cv;
    cv.u4.x = pk2(r[0], r[1]);
    cv.u4.y = pk2(r[2], r[3]);
    cv.u4.z = pk2(r[4], r[5]);
    cv.u4.w = pk2(r[6], r[7]);
    return cv.s8;
}

static __device__ __forceinline__ float sigmoid_f(float x) {
    return 1.0f / (1.0f + __expf(-x));
}
static __device__ __forceinline__ float tanh_f(float x) {
    float ax = fabsf(x);
    float e = __expf(-2.0f * ax);
    float t = (1.0f - e) / (1.0f + e);
    return copysignf(t, x);
}

// ---------------------------------------------------------------------------
// Single fused kernel, barrier-free K-loop, 4 waves/SIMD.
//   r,z,n: x-phase (8 steps) accumulates x@W_i per gate into acc[3][4];
//   h-phase (8 steps) accumulates h@W_h per gate ONCE into acch[3]
//   (h rows broadcast -> identical across row-frags; added in epilogue).
// 512 threads = 8 waves (2m x 4n), wave tile 64x16: each wave OWNS its 16
// cols, loads B global->reg (24 strided dwords/step, single-buffered:
// cvt(s) frees rb, then loads(s+1) issue under MFMA(s); 4-wave TLP hides
// the latency that R12's 2-wave dbuf couldn't). A (x) in rotated LDS tile.
// BN=64 -> grid 512 = 64u x 2mb x 4nb = 2 blocks/CU (LDS 129KB, 128-reg cap
// via __launch_bounds__(512,4): acc 48A + acch 12 + rb 24 + bf 12 + ~20 addr
// fits; WRITE_SIZE is the spill sentinel). One barrier total (prologue).
// ---------------------------------------------------------------------------
__global__ __launch_bounds__(512, 4) void gru_fused(
    const float* __restrict__ x,
    const float* __restrict__ wir,
    const float* __restrict__ wiz,
    const float* __restrict__ win,
    const float* __restrict__ whr,
    const float* __restrict__ whz,
    const float* __restrict__ whn,
    const float* __restrict__ hinit,
    float* __restrict__ out) {
    __shared__ unsigned short As[32][128][8];        // [kq][row'][j]   64 KB
    __shared__ unsigned short Ht[32][8];             // h broadcast    512 B

    const int bid = blockIdx.x;
    // XCD swizzle: xcd = bid&7 owns units [xcd*8, xcd*8+8); 8 blocks/unit.
    const int idx = bid >> 3;                  // 0..63 within XCD
    const int u   = (bid & 7) * 8 + (idx >> 3);
    const int rem = idx & 7;
    const int b0  = (rem >> 2) * 128;          // batch tile 0..1
    const int o0  = (rem & 3) * 64;            // out-feature tile 0..3

    const int t    = threadIdx.x;
    const int lane = t & 63;
    const int wv   = t >> 6;                   // 8 waves: 2m x 4n
    const int wm   = wv >> 2;                  // 0/1
    const int wn   = wv & 3;                   // 0..3
    const int lg   = lane >> 4;                // k-group 0..3
    const int lr   = lane & 15;

    const float* WX[3] = {wir, wiz, win};
    const float* WH[3] = {whr, whz, whn};

    // ---- prologue: stage A (rotated frag layout) + Ht, ONE barrier ----
    {
        const int kqA = lane >> 1;             // lane owns k = lane*4..+3
        const int j0  = (lane & 1) * 4;
#pragma unroll
        for (int i = 0; i < 16; ++i) {
            const int row = wv * 16 + i;
            v4f q = *(const v4f*)(x + (size_t)(b0 + row) * (UNITS * IFEAT)
                                    + u * IFEAT + lane * 4);
            uint2 w;
            w.x = pk2(q[0], q[1]);
            w.y = pk2(q[2], q[3]);
            *(uint2*)&As[kqA][(row + kqA) & 127][j0] = w;
        }
    }
    if (t < 32) {
        const float* hp = hinit + u * IFEAT + t * 8;
        v4f q0 = *(const v4f*)hp;
        v4f q1 = *(const v4f*)(hp + 4);
        uint4 w;
        w.x = pk2(q0[0], q0[1]);
        w.y = pk2(q0[2], q0[3]);
        w.z = pk2(q1[0], q1[1]);
        w.w = pk2(q1[2], q1[3]);
        *(uint4*)&Ht[t][0] = w;
    }

    // per-thread B base offset (col = o0 + wn*16 + lr owned by this lane)
    const size_t bcolofs = (size_t)u * (IFEAT * OFEAT) + o0 + wn * 16 + lr;

    float rb[3][8];                            // single-buffered B

#define LOADB(s)                                                             \
    {                                                                        \
        const float* const* W = ((s) < 8) ? WX : WH;                         \
        const size_t boff = bcolofs + (size_t)(((s) & 7) * 4 + lg) * 8 * OFEAT; \
        _Pragma("unroll")                                                    \
        for (int g = 0; g < 3; ++g) {                                        \
            const float* p = W[g] + boff;                                    \
            _Pragma("unroll")                                                \
            for (int j = 0; j < 8; ++j) rb[g][j] = p[j * OFEAT];             \
        }                                                                    \
    }

    v4f acc[3][4];                             // [gate][mi] x-phase
    v4f acch[3];                               // [gate]     h-phase (bcast)
#pragma unroll
    for (int g = 0; g < 3; ++g)
#pragma unroll
        for (int mi = 0; mi < 4; ++mi)
            acc[g][mi] = (v4f){0.f, 0.f, 0.f, 0.f};

    LOADB(0);                                  // prefetch step 0
    __syncthreads();                           // the ONLY barrier

    // ---- K-loop: 16 steps (8 x-phase + 8 h-phase), barrier-free ----
#pragma unroll
    for (int s = 0; s < 16; ++s) {
        // cvt current B (frees rb), then next loads issue under the MFMAs
        v8s bf[3];
#pragma unroll
        for (int g = 0; g < 3; ++g) bf[g] = pk8(rb[g]);
        if (s < 15) LOADB(s + 1);

        const int kq = (s & 7) * 4 + lg;
        if (s < 8) {
            // x-phase: 4 a-frags from rotated LDS tile
#pragma unroll
            for (int mi = 0; mi < 4; ++mi) {
                v8s a = *(const v8s*)&As[kq][((wm * 64 + mi * 16 + lr) + kq) & 127][0];
#pragma unroll
                for (int g = 0; g < 3; ++g)
                    acc[g][mi] = __builtin_amdgcn_mfma_f32_16x16x32_bf16(
                        a, bf[g], acc[g][mi], 0, 0, 0);
            }
        } else {
            if (s == 8) {
#pragma unroll
                for (int g = 0; g < 3; ++g) acch[g] = (v4f){0.f, 0.f, 0.f, 0.f};
            }
            // h-phase: broadcast A, ONE MFMA per gate (rows identical)
            v8s a0h = *(const v8s*)&Ht[kq][0];
#pragma unroll
            for (int g = 0; g < 3; ++g)
                acch[g] = __builtin_amdgcn_mfma_f32_16x16x32_bf16(
                    a0h, bf[g], acch[g], 0, 0, 0);
        }
    }
#undef LOADB

    // ---- epilogue: GRU combine ----
    // C layout: col = lane&15, row = (lane>>4)*4 + reg; acch rows identical
    const int o = o0 + wn * 16 + lr;
    const float h0v = hinit[u * OFEAT + o];
    const float hr = acch[0][0];
    const float hz = acch[1][0];
    const float hn = acch[2][0];
#pragma unroll
    for (int mi = 0; mi < 4; ++mi) {
#pragma unroll
        for (int jj = 0; jj < 4; ++jj) {
            const int row = b0 + wm * 64 + mi * 16 + lg * 4 + jj;
            const float r = sigmoid_f(acc[0][mi][jj] + hr);
            const float z = sigmoid_f(acc[1][mi][jj] + hz);
            const float n = tanh_f(acc[2][mi][jj] + r * hn);
            out[(size_t)row * (UNITS * OFEAT) + u * OFEAT + o] =
                (1.0f - z) * n + z * h0v;
        }
    }
}

extern "C" void kernel_launch(void* const* d_in, const int* in_sizes, int n_in,
                              void* d_out, int out_size, void* d_ws, size_t ws_size,
                              hipStream_t stream) {
    const float* x     = (const float*)d_in[0];
    const float* w_ir  = (const float*)d_in[1];
    const float* w_iz  = (const float*)d_in[2];
    const float* w_in  = (const float*)d_in[3];
    const float* w_hr  = (const float*)d_in[4];
    const float* w_hz  = (const float*)d_in[5];
    const float* w_hn  = (const float*)d_in[6];
    const float* hinit = (const float*)d_in[7];
    float* out = (float*)d_out;

    gru_fused<<<dim3(512), dim3(512), 0, stream>>>(
        x, w_ir, w_iz, w_in, w_hr, w_hz, w_hn, hinit, out);
}

// Round 14
// 36.385 us; speedup vs baseline: 1.1728x; 1.1728x over previous
//
#include <hip/hip_runtime.h>
#include <hip/hip_bf16.h>

#define UNITS 64
#define IFEAT 256
#define OFEAT 256

typedef __attribute__((ext_vector_type(8))) short v8s;   // 8 bf16 (4 VGPRs)
typedef __attribute__((ext_vector_type(4))) float v4f;   // MFMA acc / global f32x4

// pack 2 floats -> u32 of 2 bf16 (RNE) — compiler emits v_cvt_pk_bf16_f32
static __device__ __forceinline__ unsigned int pk2(float a, float b) {
    union { __hip_bfloat162 h; unsigned int u; } c;
    c.h = __float22bfloat162_rn(float2{a, b});
    return c.u;
}
static __device__ __forceinline__ v8s pk8(const float* r) {
    union { uint4 u4; v8s s8; } cv;
    cv.u4.x = pk2(r[0], r[1]);
    cv.u4.y = pk2(r[2], r[3]);
    cv.u4.z = pk2(r[4], r[5]);
    cv.u4.w = pk2(r[6], r[7]);
    return cv.s8;
}

static __device__ __forceinline__ float sigmoid_f(float x) {
    return 1.0f / (1.0f + __expf(-x));
}
static __device__ __forceinline__ float tanh_f(float x) {
    float ax = fabsf(x);
    float e = __expf(-2.0f * ax);
    float t = (1.0f - e) / (1.0f + e);
    return copysignf(t, x);
}

// ---------------------------------------------------------------------------
// Single fused kernel, ZERO grid-level redundancy, barrier-free K-loop.
// BM=256 (FULL batch), BN=64: grid = 64u x 4nb = 256 blocks = exactly 1/CU.
// Every W element is read ONCE grid-wide (R11/R12's mb-twin x2 redundancy —
// the suspected shared wall — is gone). x-slice read by the 4 nb-blocks of a
// unit, all on one XCD (swizzle) -> HBM x1, L2 x4 (17MB slice).
// A (x) tile: 256x256 bf16 = 128KB LDS, rotated conflict-free layout, staged
// once in the prologue (the only barrier). B: per-wave in-reg double-buffered
// strided loads (R12-proven). 16 K-steps: 8 x-phase (acc[3][8]) + 8 h-phase
// (broadcast Ht, 3 MFMA/step into acch[3] — rows identical).
// 512 thr = 8 waves (2m x 4n), wave tile 128x16. 1 block/CU (LDS-forced), so
// __launch_bounds__(512,1) -> 256-reg cap at 2 waves/SIMD: acc 96+12 AGPR +
// rb dbuf 48 + bf 12 + addr ~40 ≈ 210, no spill (WRITE_SIZE sentinel).
// ---------------------------------------------------------------------------
__global__ __launch_bounds__(512, 1) void gru_fused(
    const float* __restrict__ x,
    const float* __restrict__ wir,
    const float* __restrict__ wiz,
    const float* __restrict__ win,
    const float* __restrict__ whr,
    const float* __restrict__ whz,
    const float* __restrict__ whn,
    const float* __restrict__ hinit,
    float* __restrict__ out) {
    __shared__ unsigned short As[32][256][8];        // [kq][row'][j]  128 KB
    __shared__ unsigned short Ht[32][8];             // h broadcast   512 B

    const int bid = blockIdx.x;
    // XCD swizzle: xcd = bid&7 owns units [xcd*8, xcd*8+8); 4 nb-blocks/unit
    // co-resident on that XCD -> x-slice HBM x1, L2-shared.
    const int loc = bid >> 3;                  // 0..31 within XCD
    const int u   = (bid & 7) * 8 + (loc >> 2);
    const int o0  = (loc & 3) * 64;            // out-feature tile 0..3

    const int t    = threadIdx.x;
    const int lane = t & 63;
    const int wv   = t >> 6;                   // 8 waves: 2m x 4n
    const int wm   = wv >> 2;                  // 0/1  (128-row halves)
    const int wn   = wv & 3;                   // 0..3 (16-col slices)
    const int lg   = lane >> 4;                // k-group 0..3
    const int lr   = lane & 15;

    const float* WX[3] = {wir, wiz, win};
    const float* WH[3] = {whr, whz, whn};

    // ---- prologue: stage FULL-batch A tile (rotated frag layout) + Ht ----
    {
        const int kqA = lane >> 1;             // lane owns k = lane*4..+3
        const int j0  = (lane & 1) * 4;
#pragma unroll
        for (int i = 0; i < 32; ++i) {
            const int row = wv * 32 + i;
            v4f q = *(const v4f*)(x + (size_t)row * (UNITS * IFEAT)
                                    + u * IFEAT + lane * 4);
            uint2 w;
            w.x = pk2(q[0], q[1]);
            w.y = pk2(q[2], q[3]);
            *(uint2*)&As[kqA][(row + kqA) & 255][j0] = w;
        }
    }
    if (t < 32) {
        const float* hp = hinit + u * IFEAT + t * 8;
        v4f q0 = *(const v4f*)hp;
        v4f q1 = *(const v4f*)(hp + 4);
        uint4 w;
        w.x = pk2(q0[0], q0[1]);
        w.y = pk2(q0[2], q0[3]);
        w.z = pk2(q1[0], q1[1]);
        w.w = pk2(q1[2], q1[3]);
        *(uint4*)&Ht[t][0] = w;
    }

    // per-thread B base offset (col = o0 + wn*16 + lr owned by this lane)
    const size_t bcolofs = (size_t)u * (IFEAT * OFEAT) + o0 + wn * 16 + lr;

    float rbA[3][8], rbB[3][8];                // double-buffered B (static idx)

#define LOADB(dst, s)                                                        \
    {                                                                        \
        const float* const* W = ((s) < 8) ? WX : WH;                         \
        const size_t boff = bcolofs + (size_t)(((s) & 7) * 4 + lg) * 8 * OFEAT; \
        _Pragma("unroll")                                                    \
        for (int g = 0; g < 3; ++g) {                                        \
            const float* p = W[g] + boff;                                    \
            _Pragma("unroll")                                                \
            for (int j = 0; j < 8; ++j) dst[g][j] = p[j * OFEAT];            \
        }                                                                    \
    }

    v4f acc[3][8];                             // [gate][mi] x-phase
    v4f acch[3];                               // [gate]     h-phase (bcast)
#pragma unroll
    for (int g = 0; g < 3; ++g) {
#pragma unroll
        for (int mi = 0; mi < 8; ++mi)
            acc[g][mi] = (v4f){0.f, 0.f, 0.f, 0.f};
        acch[g] = (v4f){0.f, 0.f, 0.f, 0.f};
    }

    LOADB(rbA, 0);                             // prefetch step 0
    __syncthreads();                           // the ONLY barrier

    // ---- K-loop: 16 steps (8 x-phase + 8 h-phase), barrier-free ----
#pragma unroll
    for (int s = 0; s < 16; ++s) {
        // prefetch next step's B while computing this one (dbuf, R12-proven)
        if (s < 15) {
            if (s & 1) { LOADB(rbA, s + 1); }
            else       { LOADB(rbB, s + 1); }
        }
        const float (*rb)[8] = (s & 1) ? rbB : rbA;   // folds (full unroll)

        v8s bf[3];
#pragma unroll
        for (int g = 0; g < 3; ++g) bf[g] = pk8(rb[g]);

        const int kq = (s & 7) * 4 + lg;
        if (s < 8) {
            // x-phase: 8 a-frags from rotated LDS tile, 24 MFMAs
#pragma unroll
            for (int mi = 0; mi < 8; ++mi) {
                v8s a = *(const v8s*)&As[kq][((wm * 128 + mi * 16 + lr) + kq) & 255][0];
#pragma unroll
                for (int g = 0; g < 3; ++g)
                    acc[g][mi] = __builtin_amdgcn_mfma_f32_16x16x32_bf16(
                        a, bf[g], acc[g][mi], 0, 0, 0);
            }
        } else {
            // h-phase: broadcast A, ONE MFMA per gate (rows identical)
            v8s a0h = *(const v8s*)&Ht[kq][0];
#pragma unroll
            for (int g = 0; g < 3; ++g)
                acch[g] = __builtin_amdgcn_mfma_f32_16x16x32_bf16(
                    a0h, bf[g], acch[g], 0, 0, 0);
        }
    }
#undef LOADB

    // ---- epilogue: GRU combine ----
    // C layout: col = lane&15, row = (lane>>4)*4 + reg; acch rows identical
    const int o = o0 + wn * 16 + lr;
    const float h0v = hinit[u * OFEAT + o];
    const float hr = acch[0][0];
    const float hz = acch[1][0];
    const float hn = acch[2][0];
#pragma unroll
    for (int mi = 0; mi < 8; ++mi) {
#pragma unroll
        for (int jj = 0; jj < 4; ++jj) {
            const int row = wm * 128 + mi * 16 + lg * 4 + jj;
            const float r = sigmoid_f(acc[0][mi][jj] + hr);
            const float z = sigmoid_f(acc[1][mi][jj] + hz);
            const float n = tanh_f(acc[2][mi][jj] + r * hn);
            out[(size_t)row * (UNITS * OFEAT) + u * OFEAT + o] =
                (1.0f - z) * n + z * h0v;
        }
    }
}

extern "C" void kernel_launch(void* const* d_in, const int* in_sizes, int n_in,
                              void* d_out, int out_size, void* d_ws, size_t ws_size,
                              hipStream_t stream) {
    const float* x     = (const float*)d_in[0];
    const float* w_ir  = (const float*)d_in[1];
    const float* w_iz  = (const float*)d_in[2];
    const float* w_in  = (const float*)d_in[3];
    const float* w_hr  = (const float*)d_in[4];
    const float* w_hz  = (const float*)d_in[5];
    const float* w_hn  = (const float*)d_in[6];
    const float* hinit = (const float*)d_in[7];
    float* out = (float*)d_out;

    gru_fused<<<dim3(256), dim3(512), 0, stream>>>(
        x, w_ir, w_iz, w_in, w_hr, w_hz, w_hn, hinit, out);
}